// Round 2
// baseline (294.634 us; speedup 1.0000x reference)
//
#include <hip/hip_runtime.h>

// MetricBiasUpdater: B_next = clip(alpha*B_prev - beta*relu(pairdist(H@W^T)), -10, 10)
// B=4, N=2048, D=1024, K(geom)=32. Output fp32 [4,2048,2048].
//
// R2 notes: R1 had VGPR_Count=80 with >=128 live floats needed -> acc spilled
// to scratch -> 82us latency-bound. Fixes: launch_bounds(256,2) cap=256 VGPR,
// small live ranges in gram loop, register-prefetch of the B_prev tile to
// overlap HBM with compute. k1 rewritten as pure-fp32 vector kernel.

// ---------------------------------------------------------------------------
// Kernel 1: G[row][k] = sum_d H[row][d] * W[k][d]; Q[row] = sum_k G[row][k]^2
// rows = 8192 flat, k = 32. Block = 8 rows x 32 k-threads. 1024 blocks.
// 16 independent FMA chains per thread; H read exactly once (32 MB).
// ---------------------------------------------------------------------------
__global__ __launch_bounds__(256, 4) void k1_proj(const float* __restrict__ H,
                                                  const float* __restrict__ W,
                                                  float* __restrict__ G,
                                                  float* __restrict__ Q) {
    __shared__ float sq[8][33];
    const int t = threadIdx.x;
    const int r = t & 7;           // row within block
    const int k = t >> 3;          // 0..31 geom dim
    const long row = (long)blockIdx.x * 8 + r;
    const float* __restrict__ h = H + row * 1024;
    const float* __restrict__ w = W + (long)k * 1024;

    float4 a0 = {0.f,0.f,0.f,0.f}, a1 = {0.f,0.f,0.f,0.f};
    float4 a2 = {0.f,0.f,0.f,0.f}, a3 = {0.f,0.f,0.f,0.f};

    #pragma unroll 2
    for (int d = 0; d < 1024; d += 16) {
        const float4 h0 = *(const float4*)(h + d);
        const float4 h1 = *(const float4*)(h + d + 4);
        const float4 h2 = *(const float4*)(h + d + 8);
        const float4 h3 = *(const float4*)(h + d + 12);
        const float4 w0 = *(const float4*)(w + d);
        const float4 w1 = *(const float4*)(w + d + 4);
        const float4 w2 = *(const float4*)(w + d + 8);
        const float4 w3 = *(const float4*)(w + d + 12);
        a0.x += h0.x * w0.x; a0.y += h0.y * w0.y; a0.z += h0.z * w0.z; a0.w += h0.w * w0.w;
        a1.x += h1.x * w1.x; a1.y += h1.y * w1.y; a1.z += h1.z * w1.z; a1.w += h1.w * w1.w;
        a2.x += h2.x * w2.x; a2.y += h2.y * w2.y; a2.z += h2.z * w2.z; a2.w += h2.w * w2.w;
        a3.x += h3.x * w3.x; a3.y += h3.y * w3.y; a3.z += h3.z * w3.z; a3.w += h3.w * w3.w;
    }
    const float s = ((a0.x + a0.y) + (a0.z + a0.w)) + ((a1.x + a1.y) + (a1.z + a1.w))
                  + ((a2.x + a2.y) + (a2.z + a2.w)) + ((a3.x + a3.y) + (a3.z + a3.w));

    G[row * 32 + k] = s;
    sq[r][k] = s * s;
    __syncthreads();
    if (t < 8) {
        float q = 0.f;
        #pragma unroll
        for (int kk = 0; kk < 32; ++kk) q += sq[t][kk];
        Q[(long)blockIdx.x * 8 + t] = q;
    }
}

// ---------------------------------------------------------------------------
// Kernel 2: out[b][i][j] = clip(alpha*Bp - beta*relu(q[i]+q[j]-2*G[i].G[j]))
// 128x128 tile per block, 8x8 per thread, XOR-swizzled G tiles in LDS.
// B_prev tile register-prefetched before the gram loop (HBM/compute overlap).
// ---------------------------------------------------------------------------
__global__ __launch_bounds__(256, 2) void k2_update(const float* __restrict__ Bp,
                                                    const float* __restrict__ G,
                                                    const float* __restrict__ Q,
                                                    const float* __restrict__ alphap,
                                                    const float* __restrict__ betap,
                                                    float* __restrict__ out) {
    __shared__ float4 sGi[128 * 8];   // [row][k-chunk], chunk XOR-swizzled by row>>3
    __shared__ float4 sGj[128 * 8];
    __shared__ float  sQi[128];
    __shared__ float  sQj[128];

    const int b  = blockIdx.z;
    const int i0 = blockIdx.y * 128;
    const int j0 = blockIdx.x * 128;
    const int t  = threadIdx.x;
    const int tx = t & 15;   // j-group: j = j0 + tx*8 + jj
    const int ty = t >> 4;   // i-group: i = i0 + ty*8 + ii

    // --- prefetch B_prev tile (8 rows x 2 float4 per thread) FIRST, so the
    // --- 64 KB of HBM traffic is in flight during staging + gram compute.
    float4 bv[16];
    {
        const float4* bp = (const float4*)(Bp + ((long)b * 2048 + i0 + ty * 8) * 2048 + j0);
        #pragma unroll
        for (int ii = 0; ii < 8; ++ii) {
            bv[ii * 2 + 0] = bp[(long)ii * 512 + tx * 2 + 0];
            bv[ii * 2 + 1] = bp[(long)ii * 512 + tx * 2 + 1];
        }
    }

    // --- stage G tiles into LDS (G is 1 MB, L2-hot after k1)
    const float4* Gi4 = (const float4*)(G + ((long)b * 2048 + i0) * 32);
    const float4* Gj4 = (const float4*)(G + ((long)b * 2048 + j0) * 32);
    #pragma unroll
    for (int l = 0; l < 4; ++l) {
        const int f = t + l * 256;        // 1024 float4s = 128 rows x 8 chunks
        const int r = f >> 3, c = f & 7;
        const int cs = c ^ (r >> 3) % 8;
        sGi[r * 8 + (c ^ ((r >> 3) & 7))] = Gi4[f];
        sGj[r * 8 + (c ^ ((r >> 3) & 7))] = Gj4[f];
        (void)cs;
    }
    if (t < 128) sQi[t] = Q[b * 2048 + i0 + t];
    else         sQj[t - 128] = Q[b * 2048 + j0 + (t - 128)];
    __syncthreads();

    float acc[8][8];
    #pragma unroll
    for (int ii = 0; ii < 8; ++ii)
        #pragma unroll
        for (int jj = 0; jj < 8; ++jj) acc[ii][jj] = 0.f;

    // gram loop: live set = acc(64) + gi(32) + gj(4) -> no spill at 256-cap
    #pragma unroll
    for (int c = 0; c < 8; ++c) {
        float4 gi[8];
        #pragma unroll
        for (int u = 0; u < 8; ++u) {
            const int ri = ty * 8 + u;
            gi[u] = sGi[ri * 8 + (c ^ ((ri >> 3) & 7))];   // chunk = c ^ (ty&7): conflict-free
        }
        #pragma unroll
        for (int jj = 0; jj < 8; ++jj) {
            const int rj = tx * 8 + jj;
            const float4 gj = sGj[rj * 8 + (c ^ ((rj >> 3) & 7))]; // 2-way alias: free
            #pragma unroll
            for (int ii = 0; ii < 8; ++ii)
                acc[ii][jj] += gi[ii].x * gj.x + gi[ii].y * gj.y +
                               gi[ii].z * gj.z + gi[ii].w * gj.w;
        }
    }

    const float alpha = alphap[0];
    const float beta  = betap[0];

    #pragma unroll
    for (int ii = 0; ii < 8; ++ii) {
        const int i = i0 + ty * 8 + ii;
        const long rowoff = ((long)b * 2048 + i) * 2048 + j0;
        float4* op = (float4*)(out + rowoff);
        const float qi = sQi[ty * 8 + ii];
        #pragma unroll
        for (int g = 0; g < 2; ++g) {
            const float4 bvv = bv[ii * 2 + g];
            float4 ov;
            {
                const int jj = g * 4 + 0;
                float d = fmaxf(qi + sQj[tx * 8 + jj] - 2.f * acc[ii][jj], 0.f);
                ov.x = fminf(fmaxf(alpha * bvv.x - beta * d, -10.f), 10.f);
            }
            {
                const int jj = g * 4 + 1;
                float d = fmaxf(qi + sQj[tx * 8 + jj] - 2.f * acc[ii][jj], 0.f);
                ov.y = fminf(fmaxf(alpha * bvv.y - beta * d, -10.f), 10.f);
            }
            {
                const int jj = g * 4 + 2;
                float d = fmaxf(qi + sQj[tx * 8 + jj] - 2.f * acc[ii][jj], 0.f);
                ov.z = fminf(fmaxf(alpha * bvv.z - beta * d, -10.f), 10.f);
            }
            {
                const int jj = g * 4 + 3;
                float d = fmaxf(qi + sQj[tx * 8 + jj] - 2.f * acc[ii][jj], 0.f);
                ov.w = fminf(fmaxf(alpha * bvv.w - beta * d, -10.f), 10.f);
            }
            op[tx * 2 + g] = ov;
        }
    }
}

extern "C" void kernel_launch(void* const* d_in, const int* in_sizes, int n_in,
                              void* d_out, int out_size, void* d_ws, size_t ws_size,
                              hipStream_t stream) {
    const float* H     = (const float*)d_in[0];   // [4,2048,1024]
    const float* Bp    = (const float*)d_in[1];   // [4,2048,2048]
    const float* W     = (const float*)d_in[2];   // [32,1024]
    const float* alpha = (const float*)d_in[3];
    const float* beta  = (const float*)d_in[4];
    float* out = (float*)d_out;

    float* G = (float*)d_ws;          // [8192][32] fp32 = 1 MB
    float* Q = G + 8192 * 32;         // [8192] row sums of squares

    k1_proj<<<1024, 256, 0, stream>>>(H, W, G, Q);

    dim3 g2(16, 16, 4);               // j-tiles, i-tiles, batch
    k2_update<<<g2, 256, 0, stream>>>(Bp, G, Q, alpha, beta, out);
}

// Round 4
// 194.626 us; speedup vs baseline: 1.5139x; 1.5139x over previous
//
#include <hip/hip_runtime.h>

// MetricBiasUpdater: B_next = clip(alpha*B_prev - beta*relu(pairdist(H@W^T)), -10, 10)
// B=4, N=2048, D=1024, K(geom)=32. Output fp32 [4,2048,2048].
//
// R4 = R3 resubmitted (R3 bench died in a harness-side Trio exception, no
// kernel signal; source audited for OOB/barrier hazards — none found).
// R3 notes:
//  - R2 k1 failed: VGPR=32 -> compiler serialized loads; per-lane row-strided
//    reads were uncoalesced. Now: LDS-staged MFMA GEMM, flat-index coalesced
//    staging, 512 blocks x 128 thr.
//  - R2 k2 failed: bv[16] prefetch pinned 64 VGPRs (+ (256,2)). Now: R1
//    structure (known-good traffic), no prefetch, launch_bounds(256,3)
//    -> VGPR cap 170 > ~110 live -> no spill, 3 blocks/CU.

typedef __attribute__((ext_vector_type(8))) short short8;   // 8 bf16 (4 VGPRs)
typedef __attribute__((ext_vector_type(4))) short short4v;  // 4 bf16 (8B)
typedef __attribute__((ext_vector_type(4))) float floatx4;  // MFMA acc

static __device__ __forceinline__ short bf16_bits(float f) {
    union { float f; unsigned int u; } v; v.f = f;
    unsigned int u = v.u;
    u += 0x7FFFu + ((u >> 16) & 1u);   // round-to-nearest-even
    return (short)(u >> 16);
}

// ---------------------------------------------------------------------------
// Kernel 1: G[row][k] = sum_d H[row][d]*W[k][d]; Q[row] = sum_k G[row][k]^2
// MFMA 16x16x32 bf16. Block = 128 thr = 2 waves, 16-row M-tile, N=32 split
// as wave0 -> n 0..15, wave1 -> n 16..31. K-loop: 16 chunks of 64 d.
// ---------------------------------------------------------------------------
__global__ __launch_bounds__(128, 2) void k1_proj(const float* __restrict__ H,
                                                  const float* __restrict__ W,
                                                  float* __restrict__ G,
                                                  float* __restrict__ Q) {
    __shared__ short sA[16 * 72];   // [row][d] bf16, stride 72 (144B, 16B-aligned)
    __shared__ short sB[32 * 72];   // [n][d] bf16
    __shared__ float sG[16 * 36];   // epilogue: fp32 G tile, stride 36

    const int t    = threadIdx.x;
    const int wv   = t >> 6;        // n-tile select (0/1)
    const int lane = t & 63;
    const int lm   = lane & 15;     // A row / B col within tile
    const int quad = lane >> 4;
    const long row0 = (long)blockIdx.x * 16;

    floatx4 acc = {0.f, 0.f, 0.f, 0.f};

    for (int ch = 0; ch < 16; ++ch) {
        const int d0 = ch * 64;
        // coalesced staging loads: consecutive t -> consecutive float4
        float4 ph[2], pw[4];
        #pragma unroll
        for (int i = 0; i < 2; ++i) {           // H tile: 16 rows x 16 float4
            const int f = t + i * 128;
            ph[i] = *(const float4*)(H + (row0 + (f >> 4)) * 1024 + d0 + (f & 15) * 4);
        }
        #pragma unroll
        for (int i = 0; i < 4; ++i) {           // W tile: 32 rows x 16 float4
            const int f = t + i * 128;
            pw[i] = *(const float4*)(W + (long)(f >> 4) * 1024 + d0 + (f & 15) * 4);
        }

        __syncthreads();   // previous chunk's MFMA reads complete
        #pragma unroll
        for (int i = 0; i < 2; ++i) {
            const int f = t + i * 128;
            short4v s;
            s[0] = bf16_bits(ph[i].x); s[1] = bf16_bits(ph[i].y);
            s[2] = bf16_bits(ph[i].z); s[3] = bf16_bits(ph[i].w);
            *(short4v*)(sA + (f >> 4) * 72 + (f & 15) * 4) = s;
        }
        #pragma unroll
        for (int i = 0; i < 4; ++i) {
            const int f = t + i * 128;
            short4v s;
            s[0] = bf16_bits(pw[i].x); s[1] = bf16_bits(pw[i].y);
            s[2] = bf16_bits(pw[i].z); s[3] = bf16_bits(pw[i].w);
            *(short4v*)(sB + (f >> 4) * 72 + (f & 15) * 4) = s;
        }
        __syncthreads();   // tiles visible

        // fragment convention verified in R1: A row=lm, k=quad*8+j; B col=lm
        const short8 a0 = *(const short8*)(sA + lm * 72 + quad * 8);
        const short8 b0 = *(const short8*)(sB + (wv * 16 + lm) * 72 + quad * 8);
        acc = __builtin_amdgcn_mfma_f32_16x16x32_bf16(a0, b0, acc, 0, 0, 0);
        const short8 a1 = *(const short8*)(sA + lm * 72 + 32 + quad * 8);
        const short8 b1 = *(const short8*)(sB + (wv * 16 + lm) * 72 + 32 + quad * 8);
        acc = __builtin_amdgcn_mfma_f32_16x16x32_bf16(a1, b1, acc, 0, 0, 0);
    }

    // epilogue: C layout col = lane&15, row = quad*4 + reg (measured m89)
    __syncthreads();
    #pragma unroll
    for (int r = 0; r < 4; ++r)
        sG[(quad * 4 + r) * 36 + wv * 16 + lm] = acc[r];
    __syncthreads();

    if (t < 16) {
        float q = 0.f;
        #pragma unroll
        for (int k = 0; k < 32; ++k) { const float v = sG[t * 36 + k]; q += v * v; }
        Q[row0 + t] = q;
    }
    {   // coalesced G write: 128 float4 = 16 rows x 8 chunks
        const int r = t >> 3, c4 = t & 7;
        const float4 v = *(const float4*)(sG + r * 36 + c4 * 4);
        *(float4*)(G + (row0 + r) * 32 + c4 * 4) = v;
    }
}

// ---------------------------------------------------------------------------
// Kernel 2: out[b][i][j] = clip(alpha*Bp - beta*relu(q[i]+q[j]-2*G[i].G[j]))
// 128x128 tile per block, 8x8 per thread, XOR-swizzled G tiles in LDS.
// launch_bounds(256,3): VGPR cap 170 -> no spill at ~110 live, 3 blocks/CU.
// ---------------------------------------------------------------------------
__global__ __launch_bounds__(256, 3) void k2_update(const float* __restrict__ Bp,
                                                    const float* __restrict__ G,
                                                    const float* __restrict__ Q,
                                                    const float* __restrict__ alphap,
                                                    const float* __restrict__ betap,
                                                    float* __restrict__ out) {
    __shared__ float4 sGi[128 * 8];   // [row][k-chunk], chunk XOR-swizzled by row>>3
    __shared__ float4 sGj[128 * 8];
    __shared__ float  sQi[128];
    __shared__ float  sQj[128];

    const int b  = blockIdx.z;
    const int i0 = blockIdx.y * 128;
    const int j0 = blockIdx.x * 128;
    const int t  = threadIdx.x;
    const int tx = t & 15;   // j-group: j = j0 + tx*8 + jj
    const int ty = t >> 4;   // i-group: i = i0 + ty*8 + ii

    const float4* Gi4 = (const float4*)(G + ((long)b * 2048 + i0) * 32);
    const float4* Gj4 = (const float4*)(G + ((long)b * 2048 + j0) * 32);
    #pragma unroll
    for (int l = 0; l < 4; ++l) {
        const int f = t + l * 256;        // 1024 float4 = 128 rows x 8 chunks
        const int r = f >> 3, c = f & 7;
        const int cs = c ^ ((r >> 3) & 7);
        sGi[r * 8 + cs] = Gi4[f];
        sGj[r * 8 + cs] = Gj4[f];
    }
    if (t < 128) sQi[t] = Q[b * 2048 + i0 + t];
    else         sQj[t - 128] = Q[b * 2048 + j0 + (t - 128)];
    __syncthreads();

    float acc[8][8];
    #pragma unroll
    for (int ii = 0; ii < 8; ++ii)
        #pragma unroll
        for (int jj = 0; jj < 8; ++jj) acc[ii][jj] = 0.f;

    // gram loop: live = acc(64) + gi(32) + gj(4) + addr -> ~110 VGPR
    #pragma unroll
    for (int c = 0; c < 8; ++c) {
        float4 gi[8];
        #pragma unroll
        for (int u = 0; u < 8; ++u) {
            const int ri = ty * 8 + u;
            gi[u] = sGi[ri * 8 + (c ^ ((ri >> 3) & 7))];   // 4 ty-addrs spread: conflict-free
        }
        #pragma unroll
        for (int jj = 0; jj < 8; ++jj) {
            const int rj = tx * 8 + jj;
            const float4 gj = sGj[rj * 8 + (c ^ ((rj >> 3) & 7))]; // 2-way alias: free
            #pragma unroll
            for (int ii = 0; ii < 8; ++ii)
                acc[ii][jj] += gi[ii].x * gj.x + gi[ii].y * gj.y +
                               gi[ii].z * gj.z + gi[ii].w * gj.w;
        }
    }

    const float alpha = alphap[0];
    const float beta  = betap[0];

    #pragma unroll
    for (int ii = 0; ii < 8; ++ii) {
        const int i = i0 + ty * 8 + ii;
        const long rowoff = ((long)b * 2048 + i) * 2048 + j0;
        const float4* bp = (const float4*)(Bp + rowoff);
        float4*       op = (float4*)(out + rowoff);
        const float qi = sQi[ty * 8 + ii];
        #pragma unroll
        for (int g = 0; g < 2; ++g) {
            const float4 bv = bp[tx * 2 + g];
            float4 ov;
            {
                const int jj = g * 4 + 0;
                float d = fmaxf(qi + sQj[tx * 8 + jj] - 2.f * acc[ii][jj], 0.f);
                ov.x = fminf(fmaxf(alpha * bv.x - beta * d, -10.f), 10.f);
            }
            {
                const int jj = g * 4 + 1;
                float d = fmaxf(qi + sQj[tx * 8 + jj] - 2.f * acc[ii][jj], 0.f);
                ov.y = fminf(fmaxf(alpha * bv.y - beta * d, -10.f), 10.f);
            }
            {
                const int jj = g * 4 + 2;
                float d = fmaxf(qi + sQj[tx * 8 + jj] - 2.f * acc[ii][jj], 0.f);
                ov.z = fminf(fmaxf(alpha * bv.z - beta * d, -10.f), 10.f);
            }
            {
                const int jj = g * 4 + 3;
                float d = fmaxf(qi + sQj[tx * 8 + jj] - 2.f * acc[ii][jj], 0.f);
                ov.w = fminf(fmaxf(alpha * bv.w - beta * d, -10.f), 10.f);
            }
            op[tx * 2 + g] = ov;
        }
    }
}

extern "C" void kernel_launch(void* const* d_in, const int* in_sizes, int n_in,
                              void* d_out, int out_size, void* d_ws, size_t ws_size,
                              hipStream_t stream) {
    const float* H     = (const float*)d_in[0];   // [4,2048,1024]
    const float* Bp    = (const float*)d_in[1];   // [4,2048,2048]
    const float* W     = (const float*)d_in[2];   // [32,1024]
    const float* alpha = (const float*)d_in[3];
    const float* beta  = (const float*)d_in[4];
    float* out = (float*)d_out;

    float* G = (float*)d_ws;          // [8192][32] fp32 = 1 MB
    float* Q = G + 8192 * 32;         // [8192]

    k1_proj<<<512, 128, 0, stream>>>(H, W, G, Q);

    dim3 g2(16, 16, 4);               // j-tiles, i-tiles, batch
    k2_update<<<g2, 256, 0, stream>>>(Bp, G, Q, alpha, beta, out);
}